// Round 6
// baseline (417.766 us; speedup 1.0000x reference)
//
#include <hip/hip_runtime.h>

typedef __bf16 bf16;
typedef __bf16 bf16x8 __attribute__((ext_vector_type(8)));
typedef __bf16 bf16x4 __attribute__((ext_vector_type(4)));
typedef float f32x4 __attribute__((ext_vector_type(4)));

#define SEQ 4096
#define QKV_LD 6144
#define HNUM 16

__device__ __forceinline__ void async16(const bf16* g, bf16* l) {
    __builtin_amdgcn_global_load_lds((const __attribute__((address_space(1))) void*)g,
                                     (__attribute__((address_space(3))) void*)l, 16, 0, 0);
}

// ---------- fused prep: 3x f32->bf16 cast + RoPE cos/sin table ----------
// blocks [0,4096): X ; [4096,10240): Wqkv ; [10240,12288): Wo ; [12288,13312): table
__global__ __launch_bounds__(256) void prep(const float* __restrict__ X, bf16* __restrict__ Xb,
                                            const float* __restrict__ Wq, bf16* __restrict__ Wqb,
                                            const float* __restrict__ Wo, bf16* __restrict__ Wob,
                                            float* __restrict__ T) {
    const int b = blockIdx.x, t = threadIdx.x;
    if (b < 12288) {
        const float* src;
        bf16* dst;
        int off;
        if (b < 4096)       { src = X;  dst = Xb;  off = b; }
        else if (b < 10240) { src = Wq; dst = Wqb; off = b - 4096; }
        else                { src = Wo; dst = Wob; off = b - 10240; }
        int i = (off * 256 + t) * 8;
        f32x4 a = *(const f32x4*)(src + i);
        f32x4 c = *(const f32x4*)(src + i + 4);
        bf16x8 w;
#pragma unroll
        for (int j = 0; j < 4; j++) { w[j] = (bf16)a[j]; w[4 + j] = (bf16)c[j]; }
        *(bf16x8*)(dst + i) = w;
    } else {
        int i = (b - 12288) * 256 + t;   // 0 .. 4096*64-1
        int s = i >> 6, d = i & 63;
        float inv_freq = powf(10000.0f, -(float)d * (1.0f / 64.0f));
        float ang = (float)s * inv_freq;
        T[2 * i]     = cosf(ang);
        T[2 * i + 1] = sinf(ang);
    }
}

// ================= 256x256 8-phase GEMM (m201 template) =====================
// Wave B-fragment columns: wave wc -> head (wc>>1), intra-head base (wc&1)*32,
// fragments at +{0,16,64,80}. BIJECTIVE over the 256-col tile (verified:
// wc0:{0,16,64,80} wc1:{32,48,96,112} wc2:{128,144,192,208} wc3:{160,176,
// 224,240}); each thread holds both RoPE-pair halves (d, d+64) in-register
// (acc[.][0]/acc[.][2], acc[.][1]/acc[.][3]) -> RoPE fused into epilogue for
// Q,K col-blocks (bn<4096). XCD-chunked job swizzle for B-panel L2 residency.
__device__ __forceinline__ bf16x8 ldfrag(const bf16* slot, int row, int qd) {
    int lin  = row * 64 + qd * 16;            // [256][32] bf16, 64 B rows
    int phys = lin ^ (((lin >> 9) & 1) << 5);
    return *(const bf16x8*)((const char*)slot + phys);
}

#define STAGE2(SG, SGR0, STT, SKK, SBUF, SMAT)                                  \
    {                                                                           \
        int tcl = (STT) < NT ? (STT) : NT - 1;                                  \
        const bf16* gsrc = (SG) + (size_t)(SGR0)*K + tcl * 64 + (SKK)*32;       \
        bf16* sl = &LDS[SBUF][SMAT][SKK][0];                                    \
        async16(gsrc + g0, (bf16*)((char*)sl + lb0));                           \
        async16(gsrc + g1, (bf16*)((char*)sl + lb1));                           \
    }

#define PHASE(QM, KKI, LOADB, SG, SGR0, STT, SKK, SBUF, SMAT, DOVM)             \
    {                                                                           \
        if (LOADB) {                                                            \
            _Pragma("unroll") for (int j = 0; j < 4; j++)                       \
                bB[j] = ldfrag(&LDS[bi][1][KKI][0],                             \
                               (wc >> 1) * 128 + (wc & 1) * 32 +                \
                                   (j & 1) * 16 + (j >> 1) * 64 + ln, qd);      \
        }                                                                       \
        bf16x8 aA[4];                                                           \
        _Pragma("unroll") for (int i = 0; i < 4; i++)                           \
            aA[i] = ldfrag(&LDS[bi][0][KKI][0],                                 \
                           wr * 128 + (QM)*64 + i * 16 + ln, qd);               \
        STAGE2(SG, SGR0, STT, SKK, SBUF, SMAT);                                 \
        __builtin_amdgcn_sched_barrier(0);                                      \
        if (DOVM) {                                                             \
            asm volatile("s_waitcnt vmcnt(4)" ::: "memory");                    \
            __builtin_amdgcn_sched_barrier(0);                                  \
        }                                                                       \
        __builtin_amdgcn_s_barrier();                                           \
        __builtin_amdgcn_sched_barrier(0);                                      \
        __builtin_amdgcn_s_setprio(1);                                          \
        _Pragma("unroll") for (int i = 0; i < 4; i++)                           \
            _Pragma("unroll") for (int j = 0; j < 4; j++)                       \
                acc[(QM)*4 + i][j] = __builtin_amdgcn_mfma_f32_16x16x32_bf16(   \
                    aA[i], bB[j], acc[(QM)*4 + i][j], 0, 0, 0);                 \
        __builtin_amdgcn_s_setprio(0);                                          \
        __builtin_amdgcn_sched_barrier(0);                                      \
        __builtin_amdgcn_s_barrier();                                           \
        __builtin_amdgcn_sched_barrier(0);                                      \
    }

template <int ROPE>
__global__ __launch_bounds__(512, 2) void gemm256_nt(const bf16* __restrict__ A,
                                                     const bf16* __restrict__ B,
                                                     bf16* __restrict__ C,
                                                     int M, int N, int K,
                                                     const float* __restrict__ T) {
    __shared__ __align__(16) bf16 LDS[2][2][2][256 * 32];  // 128 KiB
    const int tid  = threadIdx.x;
    const int wave = tid >> 6, lane = tid & 63;
    const int qd = lane >> 4, ln = lane & 15;
    const int wr = wave >> 2, wc = wave & 3;
    // XCD-chunked job swizzle (assumes xcd = lin % 8; bijective since nwg%8==0)
    const int lin = blockIdx.x + gridDim.x * blockIdx.y;
    const int nwg = gridDim.x * gridDim.y;
    const int job = (lin & 7) * (nwg >> 3) + (lin >> 3);
    const int bm = (job % gridDim.x) * 256;
    const int bn = (job / gridDim.x) * 256;
    const int NT = K >> 6;

    const int seg0 = wave * 2, seg1 = seg0 + 1;
    const int Pr0 = seg0 * 1024 + lane * 16;
    const int Pr1 = seg1 * 1024 + lane * 16;
    const int Lr0 = Pr0 ^ (((Pr0 >> 9) & 1) << 5);
    const int Lr1 = Pr1 ^ (((Pr1 >> 9) & 1) << 5);
    const size_t g0 = (size_t)(Lr0 >> 6) * K + ((Lr0 & 63) >> 1);
    const size_t g1 = (size_t)(Lr1 >> 6) * K + ((Lr1 & 63) >> 1);
    const int lb0 = seg0 * 1024, lb1 = seg1 * 1024;

    f32x4 acc[8][4] = {};

    STAGE2(A, bm, 0, 0, 0, 0);
    STAGE2(B, bn, 0, 0, 0, 1);
    STAGE2(A, bm, 0, 1, 0, 0);
    STAGE2(B, bn, 0, 1, 0, 1);
    STAGE2(A, bm, 1, 0, 1, 0);
    STAGE2(B, bn, 1, 0, 1, 1);
    __builtin_amdgcn_sched_barrier(0);
    asm volatile("s_waitcnt vmcnt(4)" ::: "memory");
    __builtin_amdgcn_sched_barrier(0);
    __builtin_amdgcn_s_barrier();
    __builtin_amdgcn_sched_barrier(0);

    for (int t = 0; t < NT; ++t) {
        const int bi = t & 1;
        bf16x8 bB[4];
        PHASE(0, 0, 1, A, bm, t + 1, 1, bi ^ 1, 0, 0)
        PHASE(1, 0, 0, B, bn, t + 1, 1, bi ^ 1, 1, 0)
        PHASE(0, 1, 1, A, bm, t + 2, 0, bi,     0, 0)
        PHASE(1, 1, 0, B, bn, t + 2, 0, bi,     1, 1)
    }
    asm volatile("s_waitcnt vmcnt(0)" ::: "memory");

    // epilogue: cols bn + (wc>>1)*128 + (wc&1)*32 + ln + {0,16,64,80}
    const int colb = bn + (wc >> 1) * 128 + (wc & 1) * 32 + ln;
    if (ROPE && bn < 4096) {
        const float2* T2 = (const float2*)T;
        const int d0 = (wc & 1) * 32 + ln;   // (colb mod 128) in [0,64)
#pragma unroll
        for (int mi = 0; mi < 8; mi++)
#pragma unroll
            for (int r = 0; r < 4; r++) {
                int row = bm + wr * 128 + mi * 16 + qd * 4 + r;
                float2 cs0 = T2[(size_t)row * 64 + d0];
                float2 cs1 = T2[(size_t)row * 64 + d0 + 16];
                float a0 = acc[mi][0][r], b0 = acc[mi][2][r];
                float a1 = acc[mi][1][r], b1 = acc[mi][3][r];
                size_t o = (size_t)row * N + colb;
                C[o]      = (bf16)(a0 * cs0.x - b0 * cs0.y);
                C[o + 64] = (bf16)(b0 * cs0.x + a0 * cs0.y);
                C[o + 16] = (bf16)(a1 * cs1.x - b1 * cs1.y);
                C[o + 80] = (bf16)(b1 * cs1.x + a1 * cs1.y);
            }
    } else {
#pragma unroll
        for (int mi = 0; mi < 8; mi++)
#pragma unroll
            for (int r = 0; r < 4; r++) {
                size_t o = (size_t)(bm + wr * 128 + mi * 16 + qd * 4 + r) * N + colb;
                C[o]      = (bf16)acc[mi][0][r];
                C[o + 16] = (bf16)acc[mi][1][r];
                C[o + 64] = (bf16)acc[mi][2][r];
                C[o + 80] = (bf16)acc[mi][3][r];
            }
    }
}

// ================= 128x256 2-phase GEMM (GEMM2: exactly 1 round) ============
__device__ __forceinline__ bf16x8 ldfragB(const bf16* slot, int row, int qd) {
    int lin  = row * 64 + qd * 16;
    int phys = lin ^ (((lin >> 9) & 1) << 5);
    return *(const bf16x8*)((const char*)slot + phys);
}

#define STG(TT, KKI, BUF)                                                      \
    {                                                                          \
        int tcl = (TT) < NT ? (TT) : NT - 1;                                   \
        const bf16* As = A + (size_t)bm * K + tcl * 64 + (KKI)*32;             \
        const bf16* Bs = B + (size_t)bn * K + tcl * 64 + (KKI)*32;             \
        async16(As + gA,  (bf16*)((char*)&LA[BUF][KKI][0] + lbA));             \
        async16(Bs + gB0, (bf16*)((char*)&LB[BUF][KKI][0] + lbB0));            \
        async16(Bs + gB1, (bf16*)((char*)&LB[BUF][KKI][0] + lbB1));            \
    }

#define PH(KKI, TT, SKK, SBUF, DOVM)                                           \
    {                                                                          \
        bf16x8 aA[4], bB[4];                                                   \
        _Pragma("unroll") for (int i = 0; i < 4; i++)                          \
            aA[i] = ldfragB(&LA[bi][KKI][0], wr * 64 + i * 16 + ln, qd);       \
        _Pragma("unroll") for (int j = 0; j < 4; j++)                          \
            bB[j] = ldfragB(&LB[bi][KKI][0], wc * 64 + j * 16 + ln, qd);       \
        STG(TT, SKK, SBUF);                                                    \
        __builtin_amdgcn_sched_barrier(0);                                     \
        if (DOVM) {                                                            \
            asm volatile("s_waitcnt vmcnt(3)" ::: "memory");                   \
            __builtin_amdgcn_sched_barrier(0);                                 \
        }                                                                      \
        __builtin_amdgcn_s_barrier();                                          \
        __builtin_amdgcn_sched_barrier(0);                                     \
        __builtin_amdgcn_s_setprio(1);                                         \
        _Pragma("unroll") for (int i = 0; i < 4; i++)                          \
            _Pragma("unroll") for (int j = 0; j < 4; j++)                      \
                acc[i][j] = __builtin_amdgcn_mfma_f32_16x16x32_bf16(           \
                    aA[i], bB[j], acc[i][j], 0, 0, 0);                         \
        __builtin_amdgcn_s_setprio(0);                                         \
        __builtin_amdgcn_sched_barrier(0);                                     \
        __builtin_amdgcn_s_barrier();                                          \
        __builtin_amdgcn_sched_barrier(0);                                     \
    }

template <int C_F32>
__global__ __launch_bounds__(512, 2) void gemm128x256(const bf16* __restrict__ A,
                                                      const bf16* __restrict__ B,
                                                      void* __restrict__ Cp,
                                                      int M, int N, int K) {
    __shared__ __align__(16) bf16 LA[2][2][128 * 32];   // 32 KiB
    __shared__ __align__(16) bf16 LB[2][2][256 * 32];   // 64 KiB
    const int tid  = threadIdx.x;
    const int wave = tid >> 6, lane = tid & 63;
    const int qd = lane >> 4, ln = lane & 15;
    const int wr = wave >> 2, wc = wave & 3;
    const int lin = blockIdx.x + gridDim.x * blockIdx.y;
    const int nwg = gridDim.x * gridDim.y;
    const int job = (lin & 7) * (nwg >> 3) + (lin >> 3);
    const int bm = (job % gridDim.x) * 128;
    const int bn = (job / gridDim.x) * 256;
    const int NT = K >> 6;

    const int PrA  = wave * 1024 + lane * 16;
    const int PrB0 = (2 * wave) * 1024 + lane * 16;
    const int PrB1 = PrB0 + 1024;
    const int LrA  = PrA  ^ (((PrA  >> 9) & 1) << 5);
    const int LrB0 = PrB0 ^ (((PrB0 >> 9) & 1) << 5);
    const int LrB1 = PrB1 ^ (((PrB1 >> 9) & 1) << 5);
    const size_t gA  = (size_t)(LrA  >> 6) * K + ((LrA  & 63) >> 1);
    const size_t gB0 = (size_t)(LrB0 >> 6) * K + ((LrB0 & 63) >> 1);
    const size_t gB1 = (size_t)(LrB1 >> 6) * K + ((LrB1 & 63) >> 1);
    const int lbA = wave * 1024, lbB0 = 2 * wave * 1024, lbB1 = lbB0 + 1024;

    f32x4 acc[4][4] = {};

    STG(0, 0, 0);
    STG(0, 1, 0);
    STG(1, 0, 1);
    __builtin_amdgcn_sched_barrier(0);
    asm volatile("s_waitcnt vmcnt(3)" ::: "memory");
    __builtin_amdgcn_sched_barrier(0);
    __builtin_amdgcn_s_barrier();
    __builtin_amdgcn_sched_barrier(0);

    for (int t = 0; t < NT; ++t) {
        const int bi = t & 1;
        PH(0, t + 1, 1, bi ^ 1, 0)
        PH(1, t + 2, 0, bi,     1)
    }
    asm volatile("s_waitcnt vmcnt(0)" ::: "memory");

    const size_t cb = (size_t)(bm + wr * 64 + qd * 4) * N + (bn + wc * 64 + ln);
#pragma unroll
    for (int mi = 0; mi < 4; mi++)
#pragma unroll
        for (int j = 0; j < 4; j++)
#pragma unroll
            for (int r = 0; r < 4; r++) {
                size_t idx = cb + (size_t)(mi * 16 + r) * N + j * 16;
                if (C_F32) ((float*)Cp)[idx] = acc[mi][j][r];
                else       ((bf16*)Cp)[idx]  = (bf16)acc[mi][j][r];
            }
}

// ---------- legacy 128x128 GEMM (fallback path only) ----------
template <int A_F32, int B_F32, int C_F32>
__global__ __launch_bounds__(256) void gemm_nt(const void* __restrict__ Ap,
                                               const void* __restrict__ Bp,
                                               void* __restrict__ Cp,
                                               int M, int N, int K) {
    __shared__ __align__(16) bf16 sA[128 * 32];
    __shared__ __align__(16) bf16 sB[128 * 32];
    const int tid  = threadIdx.x;
    const int wave = tid >> 6, lane = tid & 63;
    const int qd = lane >> 4, ln = lane & 15;
    const int bm = blockIdx.x * 128, bn = blockIdx.y * 128;
    const int wm = (wave >> 1) * 64, wn = (wave & 1) * 64;

    const int srow = wave * 16 + (lane >> 2);
    const int scol = (lane & 3) * 8;
    const size_t rowoff = (size_t)srow * K + scol;
    const size_t rowskip = (size_t)64 * K;

    const bf16* Ab = (const bf16*)Ap + (size_t)bm * K + rowoff;
    const bf16* Bb = (const bf16*)Bp + (size_t)bn * K + rowoff;
    const float* Af = (const float*)Ap + (size_t)bm * K + rowoff;
    const float* Bf = (const float*)Bp + (size_t)bn * K + rowoff;
    bf16* sAd0 = &sA[(wave * 16) * 32];
    bf16* sAd1 = &sA[(64 + wave * 16) * 32];
    bf16* sBd0 = &sB[(wave * 16) * 32];
    bf16* sBd1 = &sB[(64 + wave * 16) * 32];
    bf16* sAw0 = &sA[srow * 32 + scol];
    bf16* sAw1 = &sA[(64 + srow) * 32 + scol];
    bf16* sBw0 = &sB[srow * 32 + scol];
    bf16* sBw1 = &sB[(64 + srow) * 32 + scol];

    f32x4 acc[4][4] = {};
    for (int k0 = 0; k0 < K; k0 += 32) {
        if (A_F32) {
            f32x4 u0 = *(const f32x4*)(Af + k0);
            f32x4 u1 = *(const f32x4*)(Af + k0 + 4);
            f32x4 u2 = *(const f32x4*)(Af + rowskip + k0);
            f32x4 u3 = *(const f32x4*)(Af + rowskip + k0 + 4);
            bf16x8 w0, w1;
#pragma unroll
            for (int i = 0; i < 4; i++) { w0[i] = (bf16)u0[i]; w0[4 + i] = (bf16)u1[i];
                                          w1[i] = (bf16)u2[i]; w1[4 + i] = (bf16)u3[i]; }
            *(bf16x8*)sAw0 = w0;
            *(bf16x8*)sAw1 = w1;
        } else {
            async16(Ab + k0, sAd0);
            async16(Ab + rowskip + k0, sAd1);
        }
        if (B_F32) {
            f32x4 u0 = *(const f32x4*)(Bf + k0);
            f32x4 u1 = *(const f32x4*)(Bf + k0 + 4);
            f32x4 u2 = *(const f32x4*)(Bf + rowskip + k0);
            f32x4 u3 = *(const f32x4*)(Bf + rowskip + k0 + 4);
            bf16x8 w0, w1;
#pragma unroll
            for (int i = 0; i < 4; i++) { w0[i] = (bf16)u0[i]; w0[4 + i] = (bf16)u1[i];
                                          w1[i] = (bf16)u2[i]; w1[4 + i] = (bf16)u3[i]; }
            *(bf16x8*)sBw0 = w0;
            *(bf16x8*)sBw1 = w1;
        } else {
            async16(Bb + k0, sBd0);
            async16(Bb + rowskip + k0, sBd1);
        }
        __syncthreads();
        bf16x8 af[4], bfr[4];
#pragma unroll
        for (int i = 0; i < 4; i++)
            af[i] = *(const bf16x8*)&sA[(wm + i * 16 + ln) * 32 + qd * 8];
#pragma unroll
        for (int j = 0; j < 4; j++)
            bfr[j] = *(const bf16x8*)&sB[(wn + j * 16 + ln) * 32 + qd * 8];
#pragma unroll
        for (int i = 0; i < 4; i++)
#pragma unroll
            for (int j = 0; j < 4; j++)
                acc[i][j] = __builtin_amdgcn_mfma_f32_16x16x32_bf16(af[i], bfr[j], acc[i][j], 0, 0, 0);
        __syncthreads();
    }
    const size_t cbase = (size_t)(bm + wm + qd * 4) * N + (bn + wn + ln);
#pragma unroll
    for (int i = 0; i < 4; i++)
#pragma unroll
        for (int j = 0; j < 4; j++)
#pragma unroll
            for (int r = 0; r < 4; r++) {
                size_t idx = cbase + (size_t)(i * 16 + r) * N + j * 16;
                if (C_F32) ((float*)Cp)[idx] = acc[i][j][r];
                else       ((bf16*)Cp)[idx] = (bf16)acc[i][j][r];
            }
}

// ---------- V transpose: QKV V-section [4096 s][2048 dh] -> VT [2048 dh][4096 s] ----------
__global__ __launch_bounds__(256) void transpose_v(const bf16* __restrict__ QKV,
                                                   bf16* __restrict__ VT) {
    __shared__ bf16 tl[64][65];
    const int b2 = blockIdx.x;
    const int s0 = (b2 & 63) * 64;
    const int d0 = (b2 >> 6) * 64;
    const int r = threadIdx.x >> 3, c = threadIdx.x & 7;
#pragma unroll
    for (int u = 0; u < 2; u++) {
        bf16x8 v = *(const bf16x8*)(QKV + (size_t)(s0 + u * 32 + r) * QKV_LD + 4096 + d0 + c * 8);
#pragma unroll
        for (int e = 0; e < 8; e++) tl[u * 32 + r][c * 8 + e] = v[e];
    }
    __syncthreads();
#pragma unroll
    for (int u = 0; u < 2; u++) {
        bf16x8 w;
#pragma unroll
        for (int e = 0; e < 8; e++) w[e] = tl[c * 8 + e][u * 32 + r];
        *(bf16x8*)(VT + (size_t)(d0 + u * 32 + r) * SEQ + s0 + c * 8) = w;
    }
}

// ---------- RoPE, inline trig (fallback path only) ----------
__global__ __launch_bounds__(256) void rope_k_inline(bf16* __restrict__ QKV) {
    const int s  = blockIdx.x;
    const int t  = threadIdx.x;
    const int hh = (blockIdx.y << 2) + (t >> 6);
    const int d  = t & 63;
    bf16* p = QKV + (size_t)s * QKV_LD + hh * 128 + d;
    float x0 = (float)p[0];
    float x1 = (float)p[64];
    float inv_freq = powf(10000.0f, -(float)d * (1.0f / 64.0f));
    float ang = (float)s * inv_freq;
    float c = cosf(ang), sn = sinf(ang);
    p[0]  = (bf16)(x0 * c - x1 * sn);
    p[64] = (bf16)(x1 * c + x0 * sn);
}

// ---------- causal flash attention, pipelined, 128 q-rows/block ----------
// Complementary pairing: blocks (x,y) and (x,y+16) co-reside on a CU; map
// y<16 -> qtile 31-y, y>=16 -> qtile y-16 so per-CU pair weight is constant.
template <int USE_VT>
__global__ __launch_bounds__(256, 2) void flash_attn(const bf16* __restrict__ QKV,
                                                     const bf16* __restrict__ VT,
                                                     bf16* __restrict__ O) {
    __shared__ __align__(16) bf16 sK[64 * 128];
    __shared__ __align__(16) bf16 sV[128 * 64];
    __shared__ __align__(16) bf16 sP[4][32 * 64];
    const int tid  = threadIdx.x;
    const int wave = tid >> 6, lane = tid & 63;
    const int qd = lane >> 4, ln = lane & 15;
    const int h  = blockIdx.x;
    const int y  = blockIdx.y;
    const int qtile = (y < 16) ? (31 - y) : (y - 16);
    const int qw0 = qtile * 128 + wave * 32;
    const int nkv = 2 * qtile + 2;
    const float scale = 0.08838834764831843f;

    bf16x8 Qf[2][4];
#pragma unroll
    for (int qt = 0; qt < 2; qt++) {
        const bf16* Qg = QKV + (size_t)(qw0 + qt * 16 + ln) * QKV_LD + h * 128;
#pragma unroll
        for (int ks = 0; ks < 4; ks++) {
            bf16x8 q8 = *(const bf16x8*)(Qg + ks * 32 + qd * 8);
#pragma unroll
            for (int e = 0; e < 8; e++) q8[e] = (bf16)((float)q8[e] * scale);
            Qf[qt][ks] = q8;
        }
    }

    f32x4 Oacc[2][8] = {};
    float l_i[2] = {0.0f, 0.0f};

    const int krow = tid >> 4;
    const int kblk = tid & 15;
    const int vrow = tid >> 3;
    const int vblk = tid & 7;
    const int vd   = tid & 127;
    const int vh   = tid >> 7;
    const bf16* Kg  = QKV + 2048 + h * 128;
    const bf16* Vg  = QKV + 4096 + h * 128;
    const bf16* VTg = VT + (size_t)h * 128 * SEQ;

    bf16x8 Kpre[4], Vpre[4];
#pragma unroll
    for (int rr = 0; rr < 4; rr++)
        Kpre[rr] = *(const bf16x8*)(Kg + (size_t)(rr * 16 + krow) * QKV_LD + kblk * 8);
    if (USE_VT) {
#pragma unroll
        for (int u = 0; u < 4; u++)
            Vpre[u] = *(const bf16x8*)(VTg + (size_t)(u * 32 + vrow) * SEQ + vblk * 8);
    } else {
#pragma unroll
        for (int u = 0; u < 4; u++)
#pragma unroll
            for (int j = 0; j < 8; j++)
                Vpre[u][j] = Vg[(size_t)(vh * 32 + u * 8 + j) * QKV_LD + vd];
    }

    for (int kt = 0; kt < nkv; kt++) {
        const int kbase = kt * 64;
#pragma unroll
        for (int rr = 0; rr < 4; rr++) {
            int kv = rr * 16 + krow;
            *(bf16x8*)&sK[kv * 128 + ((kblk ^ (kv & 7)) * 8)] = Kpre[rr];
        }
        if (USE_VT) {
#pragma unroll
            for (int u = 0; u < 4; u++) {
                int d = u * 32 + vrow;
                *(bf16x8*)&sV[d * 64 + ((vblk ^ (d & 7)) * 8)] = Vpre[u];
            }
        } else {
#pragma unroll
            for (int u = 0; u < 4; u++)
                *(bf16x8*)&sV[vd * 64 + (((vh * 4 + u) ^ (vd & 7)) * 8)] = Vpre[u];
        }
        __syncthreads();
        if (kt + 1 < nkv) {
            const int nb = kbase + 64;
#pragma unroll
            for (int rr = 0; rr < 4; rr++)
                Kpre[rr] = *(const bf16x8*)(Kg + (size_t)(nb + rr * 16 + krow) * QKV_LD + kblk * 8);
            if (USE_VT) {
#pragma unroll
                for (int u = 0; u < 4; u++)
                    Vpre[u] = *(const bf16x8*)(VTg + (size_t)(u * 32 + vrow) * SEQ + nb + vblk * 8);
            } else {
#pragma unroll
                for (int u = 0; u < 4; u++)
#pragma unroll
                    for (int j = 0; j < 8; j++)
                        Vpre[u][j] = Vg[(size_t)(nb + vh * 32 + u * 8 + j) * QKV_LD + vd];
            }
        }
        if (kbase <= qw0 + 31) {
            f32x4 Sacc[2][4] = {};
            __builtin_amdgcn_s_setprio(1);
#pragma unroll
            for (int ks = 0; ks < 4; ks++)
#pragma unroll
                for (int j = 0; j < 4; j++) {
                    bf16x8 af = *(const bf16x8*)&sK[(j * 16 + ln) * 128 + (((ks * 4 + qd) ^ (ln & 7)) * 8)];
                    Sacc[0][j] = __builtin_amdgcn_mfma_f32_16x16x32_bf16(af, Qf[0][ks], Sacc[0][j], 0, 0, 0);
                    Sacc[1][j] = __builtin_amdgcn_mfma_f32_16x16x32_bf16(af, Qf[1][ks], Sacc[1][j], 0, 0, 0);
                }
            __builtin_amdgcn_s_setprio(0);
#pragma unroll
            for (int qt = 0; qt < 2; qt++) {
                const int qs = qw0 + qt * 16;
                if (kbase + 63 > qs) {
#pragma unroll
                    for (int j = 0; j < 4; j++)
#pragma unroll
                        for (int r = 0; r < 4; r++)
                            if (kbase + j * 16 + qd * 4 + r > qs + ln) Sacc[qt][j][r] = -1e30f;
                }
                float psum = 0.0f;
#pragma unroll
                for (int j = 0; j < 4; j++) {
                    bf16x4 p4;
#pragma unroll
                    for (int r = 0; r < 4; r++) {
                        float p = __expf(Sacc[qt][j][r]);
                        psum += p;
                        p4[r] = (bf16)p;
                    }
                    int blk = (j * 2 + (qd >> 1)) ^ (ln & 7);
                    *(bf16x4*)&sP[wave][(qt * 16 + ln) * 64 + blk * 8 + (qd & 1) * 4] = p4;
                }
                psum += __shfl_xor(psum, 16);
                psum += __shfl_xor(psum, 32);
                l_i[qt] += psum;
            }
            __builtin_amdgcn_s_setprio(1);
#pragma unroll
            for (int ks = 0; ks < 2; ks++) {
                bf16x8 pf0 = *(const bf16x8*)&sP[wave][(0 * 16 + ln) * 64 + (((ks * 4 + qd) ^ (ln & 7)) * 8)];
                bf16x8 pf1 = *(const bf16x8*)&sP[wave][(1 * 16 + ln) * 64 + (((ks * 4 + qd) ^ (ln & 7)) * 8)];
#pragma unroll
                for (int dt = 0; dt < 8; dt++) {
                    bf16x8 vf = *(const bf16x8*)&sV[(dt * 16 + ln) * 64 + (((ks * 4 + qd) ^ (ln & 7)) * 8)];
                    Oacc[0][dt] = __builtin_amdgcn_mfma_f32_16x16x32_bf16(pf0, vf, Oacc[0][dt], 0, 0, 0);
                    Oacc[1][dt] = __builtin_amdgcn_mfma_f32_16x16x32_bf16(pf1, vf, Oacc[1][dt], 0, 0, 0);
                }
            }
            __builtin_amdgcn_s_setprio(0);
        }
        __syncthreads();
    }
#pragma unroll
    for (int qt = 0; qt < 2; qt++) {
        float linv[4];
#pragma unroll
        for (int r = 0; r < 4; r++)
            linv[r] = 1.0f / __shfl(l_i[qt], (lane & 48) | (qd * 4 + r));
        bf16* Ob = O + (size_t)(qw0 + qt * 16 + qd * 4) * 2048 + h * 128 + ln;
#pragma unroll
        for (int dt = 0; dt < 8; dt++)
#pragma unroll
            for (int r = 0; r < 4; r++)
                Ob[(size_t)r * 2048 + dt * 16] = (bf16)(Oacc[qt][dt][r] * linv[r]);
    }
}

extern "C" void kernel_launch(void* const* d_in, const int* in_sizes, int n_in,
                              void* d_out, int out_size, void* d_ws, size_t ws_size,
                              hipStream_t stream) {
    const float* X    = (const float*)d_in[0];  // [4096][2048] f32
    const float* Wqkv = (const float*)d_in[1];  // [6144][2048] f32
    const float* Wo   = (const float*)d_in[2];  // [2048][2048] f32
    float* out = (float*)d_out;                 // [4096][2048] f32
    bf16* QKV = (bf16*)d_ws;                    // [4096][6144] bf16
    bf16* ATT = QKV + (size_t)4096 * 6144;      // [4096][2048] bf16

    const size_t nX = (size_t)4096 * 2048, nWq = (size_t)6144 * 2048, nWo = (size_t)2048 * 2048;
    const size_t need = (nX * 3 + nWq * 2 + nWo) * 2 + nX * 2;

    if (ws_size >= need) {
        bf16* Xb  = ATT + nX;
        bf16* Wqb = Xb + nX;
        bf16* Wob = Wqb + nWq;
        bf16*  VT  = Xb;            // dead after gemm1 -> reuse as VT
        float* Tab = (float*)ATT;   // ATT dead until flash -> RoPE table (2 MB)
        prep<<<13312, 256, 0, stream>>>(X, Xb, Wqkv, Wqb, Wo, Wob, Tab);
        gemm256_nt<1><<<dim3(16, 24), 512, 0, stream>>>(Xb, Wqb, QKV, 4096, 6144, 2048, Tab);
        transpose_v<<<2048, 256, 0, stream>>>(QKV, VT);
        flash_attn<1><<<dim3(HNUM, 32), 256, 0, stream>>>(QKV, VT, ATT);
        gemm128x256<1><<<dim3(32, 8), 512, 0, stream>>>(ATT, Wob, out, 4096, 2048, 2048);
    } else {
        gemm_nt<1, 1, 0><<<dim3(32, 48), 256, 0, stream>>>(X, Wqkv, QKV, 4096, 6144, 2048);
        rope_k_inline<<<dim3(4096, 8), 256, 0, stream>>>(QKV);
        flash_attn<0><<<dim3(HNUM, 32), 256, 0, stream>>>(QKV, (const bf16*)nullptr, ATT);
        gemm_nt<0, 1, 1><<<dim3(32, 16), 256, 0, stream>>>(ATT, Wo, out, 4096, 2048, 2048);
    }
}

// Round 7
// 400.964 us; speedup vs baseline: 1.0419x; 1.0419x over previous
//
#include <hip/hip_runtime.h>

typedef __bf16 bf16;
typedef __bf16 bf16x8 __attribute__((ext_vector_type(8)));
typedef __bf16 bf16x4 __attribute__((ext_vector_type(4)));
typedef float f32x4 __attribute__((ext_vector_type(4)));

#define SEQ 4096
#define QKV_LD 6144
#define HNUM 16

__device__ __forceinline__ void async16(const bf16* g, bf16* l) {
    __builtin_amdgcn_global_load_lds((const __attribute__((address_space(1))) void*)g,
                                     (__attribute__((address_space(3))) void*)l, 16, 0, 0);
}

// ---------- fused prep: 3x f32->bf16 cast + RoPE cos/sin table ----------
// blocks [0,4096): X ; [4096,10240): Wqkv ; [10240,12288): Wo ; [12288,13312): table
__global__ __launch_bounds__(256) void prep(const float* __restrict__ X, bf16* __restrict__ Xb,
                                            const float* __restrict__ Wq, bf16* __restrict__ Wqb,
                                            const float* __restrict__ Wo, bf16* __restrict__ Wob,
                                            float* __restrict__ T) {
    const int b = blockIdx.x, t = threadIdx.x;
    if (b < 12288) {
        const float* src;
        bf16* dst;
        int off;
        if (b < 4096)       { src = X;  dst = Xb;  off = b; }
        else if (b < 10240) { src = Wq; dst = Wqb; off = b - 4096; }
        else                { src = Wo; dst = Wob; off = b - 10240; }
        int i = (off * 256 + t) * 8;
        f32x4 a = *(const f32x4*)(src + i);
        f32x4 c = *(const f32x4*)(src + i + 4);
        bf16x8 w;
#pragma unroll
        for (int j = 0; j < 4; j++) { w[j] = (bf16)a[j]; w[4 + j] = (bf16)c[j]; }
        *(bf16x8*)(dst + i) = w;
    } else {
        int i = (b - 12288) * 256 + t;   // 0 .. 4096*64-1
        int s = i >> 6, d = i & 63;
        float inv_freq = powf(10000.0f, -(float)d * (1.0f / 64.0f));
        float ang = (float)s * inv_freq;
        T[2 * i]     = cosf(ang);
        T[2 * i + 1] = sinf(ang);
    }
}

// ================= 256x256 8-phase GEMM (m201 template) =====================
// Natural blockIdx mapping (XCD swizzle REVERTED: R6 measured +35% FETCH, +5us).
// Wave B-fragment columns: wave wc -> head (wc>>1), intra-head base (wc&1)*32,
// fragments at +{0,16,64,80} (bijective over 256 cols). Each thread holds both
// RoPE-pair halves (d, d+64) in-register -> RoPE fused into epilogue for Q,K
// tiles (bn<4096). V tiles (bn>=4096) are written TRANSPOSED into QKV's own
// V-section: VT(dh,s) at QKV[2*dh + (s>>11)][4096 + (s&2047)] -- bijective,
// disjoint from Q/K columns, so no transpose_v pass is needed.
__device__ __forceinline__ bf16x8 ldfrag(const bf16* slot, int row, int qd) {
    int lin  = row * 64 + qd * 16;            // [256][32] bf16, 64 B rows
    int phys = lin ^ (((lin >> 9) & 1) << 5);
    return *(const bf16x8*)((const char*)slot + phys);
}

#define STAGE2(SG, SGR0, STT, SKK, SBUF, SMAT)                                  \
    {                                                                           \
        int tcl = (STT) < NT ? (STT) : NT - 1;                                  \
        const bf16* gsrc = (SG) + (size_t)(SGR0)*K + tcl * 64 + (SKK)*32;       \
        bf16* sl = &LDS[SBUF][SMAT][SKK][0];                                    \
        async16(gsrc + g0, (bf16*)((char*)sl + lb0));                           \
        async16(gsrc + g1, (bf16*)((char*)sl + lb1));                           \
    }

#define PHASE(QM, KKI, LOADB, SG, SGR0, STT, SKK, SBUF, SMAT, DOVM)             \
    {                                                                           \
        if (LOADB) {                                                            \
            _Pragma("unroll") for (int j = 0; j < 4; j++)                       \
                bB[j] = ldfrag(&LDS[bi][1][KKI][0],                             \
                               (wc >> 1) * 128 + (wc & 1) * 32 +                \
                                   (j & 1) * 16 + (j >> 1) * 64 + ln, qd);      \
        }                                                                       \
        bf16x8 aA[4];                                                           \
        _Pragma("unroll") for (int i = 0; i < 4; i++)                           \
            aA[i] = ldfrag(&LDS[bi][0][KKI][0],                                 \
                           wr * 128 + (QM)*64 + i * 16 + ln, qd);               \
        STAGE2(SG, SGR0, STT, SKK, SBUF, SMAT);                                 \
        __builtin_amdgcn_sched_barrier(0);                                      \
        if (DOVM) {                                                             \
            asm volatile("s_waitcnt vmcnt(4)" ::: "memory");                    \
            __builtin_amdgcn_sched_barrier(0);                                  \
        }                                                                       \
        __builtin_amdgcn_s_barrier();                                           \
        __builtin_amdgcn_sched_barrier(0);                                      \
        __builtin_amdgcn_s_setprio(1);                                          \
        _Pragma("unroll") for (int i = 0; i < 4; i++)                           \
            _Pragma("unroll") for (int j = 0; j < 4; j++)                       \
                acc[(QM)*4 + i][j] = __builtin_amdgcn_mfma_f32_16x16x32_bf16(   \
                    aA[i], bB[j], acc[(QM)*4 + i][j], 0, 0, 0);                 \
        __builtin_amdgcn_s_setprio(0);                                          \
        __builtin_amdgcn_sched_barrier(0);                                      \
        __builtin_amdgcn_s_barrier();                                           \
        __builtin_amdgcn_sched_barrier(0);                                      \
    }

template <int ROPE>
__global__ __launch_bounds__(512, 2) void gemm256_nt(const bf16* __restrict__ A,
                                                     const bf16* __restrict__ B,
                                                     bf16* __restrict__ C,
                                                     int M, int N, int K,
                                                     const float* __restrict__ T) {
    __shared__ __align__(16) bf16 LDS[2][2][2][256 * 32];  // 128 KiB
    const int tid  = threadIdx.x;
    const int wave = tid >> 6, lane = tid & 63;
    const int qd = lane >> 4, ln = lane & 15;
    const int wr = wave >> 2, wc = wave & 3;
    const int bm = blockIdx.x * 256, bn = blockIdx.y * 256;
    const int NT = K >> 6;

    const int seg0 = wave * 2, seg1 = seg0 + 1;
    const int Pr0 = seg0 * 1024 + lane * 16;
    const int Pr1 = seg1 * 1024 + lane * 16;
    const int Lr0 = Pr0 ^ (((Pr0 >> 9) & 1) << 5);
    const int Lr1 = Pr1 ^ (((Pr1 >> 9) & 1) << 5);
    const size_t g0 = (size_t)(Lr0 >> 6) * K + ((Lr0 & 63) >> 1);
    const size_t g1 = (size_t)(Lr1 >> 6) * K + ((Lr1 & 63) >> 1);
    const int lb0 = seg0 * 1024, lb1 = seg1 * 1024;

    f32x4 acc[8][4] = {};

    STAGE2(A, bm, 0, 0, 0, 0);
    STAGE2(B, bn, 0, 0, 0, 1);
    STAGE2(A, bm, 0, 1, 0, 0);
    STAGE2(B, bn, 0, 1, 0, 1);
    STAGE2(A, bm, 1, 0, 1, 0);
    STAGE2(B, bn, 1, 0, 1, 1);
    __builtin_amdgcn_sched_barrier(0);
    asm volatile("s_waitcnt vmcnt(4)" ::: "memory");
    __builtin_amdgcn_sched_barrier(0);
    __builtin_amdgcn_s_barrier();
    __builtin_amdgcn_sched_barrier(0);

    for (int t = 0; t < NT; ++t) {
        const int bi = t & 1;
        bf16x8 bB[4];
        PHASE(0, 0, 1, A, bm, t + 1, 1, bi ^ 1, 0, 0)
        PHASE(1, 0, 0, B, bn, t + 1, 1, bi ^ 1, 1, 0)
        PHASE(0, 1, 1, A, bm, t + 2, 0, bi,     0, 0)
        PHASE(1, 1, 0, B, bn, t + 2, 0, bi,     1, 1)
    }
    asm volatile("s_waitcnt vmcnt(0)" ::: "memory");

    // epilogue: cols bn + (wc>>1)*128 + (wc&1)*32 + ln + {0,16,64,80}
    const int colb = bn + (wc >> 1) * 128 + (wc & 1) * 32 + ln;
    if (ROPE && bn < 4096) {
        const float2* T2 = (const float2*)T;
        const int d0 = (wc & 1) * 32 + ln;   // (colb mod 128) in [0,64)
#pragma unroll
        for (int mi = 0; mi < 8; mi++)
#pragma unroll
            for (int r = 0; r < 4; r++) {
                int row = bm + wr * 128 + mi * 16 + qd * 4 + r;
                float2 cs0 = T2[(size_t)row * 64 + d0];
                float2 cs1 = T2[(size_t)row * 64 + d0 + 16];
                float a0 = acc[mi][0][r], b0 = acc[mi][2][r];
                float a1 = acc[mi][1][r], b1 = acc[mi][3][r];
                size_t o = (size_t)row * N + colb;
                C[o]      = (bf16)(a0 * cs0.x - b0 * cs0.y);
                C[o + 64] = (bf16)(b0 * cs0.x + a0 * cs0.y);
                C[o + 16] = (bf16)(a1 * cs1.x - b1 * cs1.y);
                C[o + 80] = (bf16)(b1 * cs1.x + a1 * cs1.y);
            }
    } else if (ROPE) {
        // V tile: write transposed into QKV V-section (VT layout).
        // VT(dh, s) -> C[ (2*dh + (s>>11)) * N + 4096 + (s & 2047) ]
        bf16* Vb = C + 4096;
#pragma unroll
        for (int mi = 0; mi < 8; mi++) {
            const int row = bm + wr * 128 + mi * 16 + qd * 4;  // s, 4-aligned
            const int rhi = row >> 11;
            const int rlo = row & 2047;
#pragma unroll
            for (int j = 0; j < 4; j++) {
                const int dh = colb - 4096 + (j & 1) * 16 + (j >> 1) * 64;
                bf16x4 w;
#pragma unroll
                for (int r = 0; r < 4; r++) w[r] = (bf16)acc[mi][j][r];
                *(bf16x4*)(Vb + (size_t)(2 * dh + rhi) * N + rlo) = w;
            }
        }
    } else {
#pragma unroll
        for (int mi = 0; mi < 8; mi++)
#pragma unroll
            for (int r = 0; r < 4; r++) {
                size_t o = (size_t)(bm + wr * 128 + mi * 16 + qd * 4 + r) * N + colb;
                C[o]      = (bf16)acc[mi][0][r];
                C[o + 16] = (bf16)acc[mi][1][r];
                C[o + 64] = (bf16)acc[mi][2][r];
                C[o + 80] = (bf16)acc[mi][3][r];
            }
    }
}

// ================= 128x256 2-phase GEMM (GEMM2: exactly 1 round) ============
__device__ __forceinline__ bf16x8 ldfragB(const bf16* slot, int row, int qd) {
    int lin  = row * 64 + qd * 16;
    int phys = lin ^ (((lin >> 9) & 1) << 5);
    return *(const bf16x8*)((const char*)slot + phys);
}

#define STG(TT, KKI, BUF)                                                      \
    {                                                                          \
        int tcl = (TT) < NT ? (TT) : NT - 1;                                   \
        const bf16* As = A + (size_t)bm * K + tcl * 64 + (KKI)*32;             \
        const bf16* Bs = B + (size_t)bn * K + tcl * 64 + (KKI)*32;             \
        async16(As + gA,  (bf16*)((char*)&LA[BUF][KKI][0] + lbA));             \
        async16(Bs + gB0, (bf16*)((char*)&LB[BUF][KKI][0] + lbB0));            \
        async16(Bs + gB1, (bf16*)((char*)&LB[BUF][KKI][0] + lbB1));            \
    }

#define PH(KKI, TT, SKK, SBUF, DOVM)                                           \
    {                                                                          \
        bf16x8 aA[4], bB[4];                                                   \
        _Pragma("unroll") for (int i = 0; i < 4; i++)                          \
            aA[i] = ldfragB(&LA[bi][KKI][0], wr * 64 + i * 16 + ln, qd);       \
        _Pragma("unroll") for (int j = 0; j < 4; j++)                          \
            bB[j] = ldfragB(&LB[bi][KKI][0], wc * 64 + j * 16 + ln, qd);       \
        STG(TT, SKK, SBUF);                                                    \
        __builtin_amdgcn_sched_barrier(0);                                     \
        if (DOVM) {                                                            \
            asm volatile("s_waitcnt vmcnt(3)" ::: "memory");                   \
            __builtin_amdgcn_sched_barrier(0);                                 \
        }                                                                      \
        __builtin_amdgcn_s_barrier();                                          \
        __builtin_amdgcn_sched_barrier(0);                                     \
        __builtin_amdgcn_s_setprio(1);                                         \
        _Pragma("unroll") for (int i = 0; i < 4; i++)                          \
            _Pragma("unroll") for (int j = 0; j < 4; j++)                      \
                acc[i][j] = __builtin_amdgcn_mfma_f32_16x16x32_bf16(           \
                    aA[i], bB[j], acc[i][j], 0, 0, 0);                         \
        __builtin_amdgcn_s_setprio(0);                                         \
        __builtin_amdgcn_sched_barrier(0);                                     \
        __builtin_amdgcn_s_barrier();                                          \
        __builtin_amdgcn_sched_barrier(0);                                     \
    }

template <int C_F32>
__global__ __launch_bounds__(512, 2) void gemm128x256(const bf16* __restrict__ A,
                                                      const bf16* __restrict__ B,
                                                      void* __restrict__ Cp,
                                                      int M, int N, int K) {
    __shared__ __align__(16) bf16 LA[2][2][128 * 32];   // 32 KiB
    __shared__ __align__(16) bf16 LB[2][2][256 * 32];   // 64 KiB
    const int tid  = threadIdx.x;
    const int wave = tid >> 6, lane = tid & 63;
    const int qd = lane >> 4, ln = lane & 15;
    const int wr = wave >> 2, wc = wave & 3;
    const int bm = blockIdx.x * 128, bn = blockIdx.y * 256;
    const int NT = K >> 6;

    const int PrA  = wave * 1024 + lane * 16;
    const int PrB0 = (2 * wave) * 1024 + lane * 16;
    const int PrB1 = PrB0 + 1024;
    const int LrA  = PrA  ^ (((PrA  >> 9) & 1) << 5);
    const int LrB0 = PrB0 ^ (((PrB0 >> 9) & 1) << 5);
    const int LrB1 = PrB1 ^ (((PrB1 >> 9) & 1) << 5);
    const size_t gA  = (size_t)(LrA  >> 6) * K + ((LrA  & 63) >> 1);
    const size_t gB0 = (size_t)(LrB0 >> 6) * K + ((LrB0 & 63) >> 1);
    const size_t gB1 = (size_t)(LrB1 >> 6) * K + ((LrB1 & 63) >> 1);
    const int lbA = wave * 1024, lbB0 = 2 * wave * 1024, lbB1 = lbB0 + 1024;

    f32x4 acc[4][4] = {};

    STG(0, 0, 0);
    STG(0, 1, 0);
    STG(1, 0, 1);
    __builtin_amdgcn_sched_barrier(0);
    asm volatile("s_waitcnt vmcnt(3)" ::: "memory");
    __builtin_amdgcn_sched_barrier(0);
    __builtin_amdgcn_s_barrier();
    __builtin_amdgcn_sched_barrier(0);

    for (int t = 0; t < NT; ++t) {
        const int bi = t & 1;
        PH(0, t + 1, 1, bi ^ 1, 0)
        PH(1, t + 2, 0, bi,     1)
    }
    asm volatile("s_waitcnt vmcnt(0)" ::: "memory");

    const size_t cb = (size_t)(bm + wr * 64 + qd * 4) * N + (bn + wc * 64 + ln);
#pragma unroll
    for (int mi = 0; mi < 4; mi++)
#pragma unroll
        for (int j = 0; j < 4; j++)
#pragma unroll
            for (int r = 0; r < 4; r++) {
                size_t idx = cb + (size_t)(mi * 16 + r) * N + j * 16;
                if (C_F32) ((float*)Cp)[idx] = acc[mi][j][r];
                else       ((bf16*)Cp)[idx]  = (bf16)acc[mi][j][r];
            }
}

// ---------- legacy 128x128 GEMM (fallback path only) ----------
template <int A_F32, int B_F32, int C_F32>
__global__ __launch_bounds__(256) void gemm_nt(const void* __restrict__ Ap,
                                               const void* __restrict__ Bp,
                                               void* __restrict__ Cp,
                                               int M, int N, int K) {
    __shared__ __align__(16) bf16 sA[128 * 32];
    __shared__ __align__(16) bf16 sB[128 * 32];
    const int tid  = threadIdx.x;
    const int wave = tid >> 6, lane = tid & 63;
    const int qd = lane >> 4, ln = lane & 15;
    const int bm = blockIdx.x * 128, bn = blockIdx.y * 128;
    const int wm = (wave >> 1) * 64, wn = (wave & 1) * 64;

    const int srow = wave * 16 + (lane >> 2);
    const int scol = (lane & 3) * 8;
    const size_t rowoff = (size_t)srow * K + scol;
    const size_t rowskip = (size_t)64 * K;

    const bf16* Ab = (const bf16*)Ap + (size_t)bm * K + rowoff;
    const bf16* Bb = (const bf16*)Bp + (size_t)bn * K + rowoff;
    const float* Af = (const float*)Ap + (size_t)bm * K + rowoff;
    const float* Bf = (const float*)Bp + (size_t)bn * K + rowoff;
    bf16* sAd0 = &sA[(wave * 16) * 32];
    bf16* sAd1 = &sA[(64 + wave * 16) * 32];
    bf16* sBd0 = &sB[(wave * 16) * 32];
    bf16* sBd1 = &sB[(64 + wave * 16) * 32];
    bf16* sAw0 = &sA[srow * 32 + scol];
    bf16* sAw1 = &sA[(64 + srow) * 32 + scol];
    bf16* sBw0 = &sB[srow * 32 + scol];
    bf16* sBw1 = &sB[(64 + srow) * 32 + scol];

    f32x4 acc[4][4] = {};
    for (int k0 = 0; k0 < K; k0 += 32) {
        if (A_F32) {
            f32x4 u0 = *(const f32x4*)(Af + k0);
            f32x4 u1 = *(const f32x4*)(Af + k0 + 4);
            f32x4 u2 = *(const f32x4*)(Af + rowskip + k0);
            f32x4 u3 = *(const f32x4*)(Af + rowskip + k0 + 4);
            bf16x8 w0, w1;
#pragma unroll
            for (int i = 0; i < 4; i++) { w0[i] = (bf16)u0[i]; w0[4 + i] = (bf16)u1[i];
                                          w1[i] = (bf16)u2[i]; w1[4 + i] = (bf16)u3[i]; }
            *(bf16x8*)sAw0 = w0;
            *(bf16x8*)sAw1 = w1;
        } else {
            async16(Ab + k0, sAd0);
            async16(Ab + rowskip + k0, sAd1);
        }
        if (B_F32) {
            f32x4 u0 = *(const f32x4*)(Bf + k0);
            f32x4 u1 = *(const f32x4*)(Bf + k0 + 4);
            f32x4 u2 = *(const f32x4*)(Bf + rowskip + k0);
            f32x4 u3 = *(const f32x4*)(Bf + rowskip + k0 + 4);
            bf16x8 w0, w1;
#pragma unroll
            for (int i = 0; i < 4; i++) { w0[i] = (bf16)u0[i]; w0[4 + i] = (bf16)u1[i];
                                          w1[i] = (bf16)u2[i]; w1[4 + i] = (bf16)u3[i]; }
            *(bf16x8*)sBw0 = w0;
            *(bf16x8*)sBw1 = w1;
        } else {
            async16(Bb + k0, sBd0);
            async16(Bb + rowskip + k0, sBd1);
        }
        __syncthreads();
        bf16x8 af[4], bfr[4];
#pragma unroll
        for (int i = 0; i < 4; i++)
            af[i] = *(const bf16x8*)&sA[(wm + i * 16 + ln) * 32 + qd * 8];
#pragma unroll
        for (int j = 0; j < 4; j++)
            bfr[j] = *(const bf16x8*)&sB[(wn + j * 16 + ln) * 32 + qd * 8];
#pragma unroll
        for (int i = 0; i < 4; i++)
#pragma unroll
            for (int j = 0; j < 4; j++)
                acc[i][j] = __builtin_amdgcn_mfma_f32_16x16x32_bf16(af[i], bfr[j], acc[i][j], 0, 0, 0);
        __syncthreads();
    }
    const size_t cbase = (size_t)(bm + wm + qd * 4) * N + (bn + wn + ln);
#pragma unroll
    for (int i = 0; i < 4; i++)
#pragma unroll
        for (int j = 0; j < 4; j++)
#pragma unroll
            for (int r = 0; r < 4; r++) {
                size_t idx = cbase + (size_t)(i * 16 + r) * N + j * 16;
                if (C_F32) ((float*)Cp)[idx] = acc[i][j][r];
                else       ((bf16*)Cp)[idx] = (bf16)acc[i][j][r];
            }
}

// ---------- RoPE, inline trig (fallback path only) ----------
__global__ __launch_bounds__(256) void rope_k_inline(bf16* __restrict__ QKV) {
    const int s  = blockIdx.x;
    const int t  = threadIdx.x;
    const int hh = (blockIdx.y << 2) + (t >> 6);
    const int d  = t & 63;
    bf16* p = QKV + (size_t)s * QKV_LD + hh * 128 + d;
    float x0 = (float)p[0];
    float x1 = (float)p[64];
    float inv_freq = powf(10000.0f, -(float)d * (1.0f / 64.0f));
    float ang = (float)s * inv_freq;
    float c = cosf(ang), sn = sinf(ang);
    p[0]  = (bf16)(x0 * c - x1 * sn);
    p[64] = (bf16)(x1 * c + x0 * sn);
}

// ---------- causal flash attention, pipelined, 128 q-rows/block ----------
// Complementary pairing: blocks (x,y) and (x,y+16) co-reside on a CU; map
// y<16 -> qtile 31-y, y>=16 -> qtile y-16 so per-CU pair weight is constant.
// USE_VT=1: V read from the in-QKV VT layout written by gemm1's epilogue:
// VT(dh, s) = QKV[2*dh + (s>>11)][4096 + (s&2047)].
template <int USE_VT>
__global__ __launch_bounds__(256, 2) void flash_attn(const bf16* __restrict__ QKV,
                                                     bf16* __restrict__ O) {
    __shared__ __align__(16) bf16 sK[64 * 128];
    __shared__ __align__(16) bf16 sV[128 * 64];
    __shared__ __align__(16) bf16 sP[4][32 * 64];
    const int tid  = threadIdx.x;
    const int wave = tid >> 6, lane = tid & 63;
    const int qd = lane >> 4, ln = lane & 15;
    const int h  = blockIdx.x;
    const int y  = blockIdx.y;
    const int qtile = (y < 16) ? (31 - y) : (y - 16);
    const int qw0 = qtile * 128 + wave * 32;
    const int nkv = 2 * qtile + 2;
    const float scale = 0.08838834764831843f;

    bf16x8 Qf[2][4];
#pragma unroll
    for (int qt = 0; qt < 2; qt++) {
        const bf16* Qg = QKV + (size_t)(qw0 + qt * 16 + ln) * QKV_LD + h * 128;
#pragma unroll
        for (int ks = 0; ks < 4; ks++) {
            bf16x8 q8 = *(const bf16x8*)(Qg + ks * 32 + qd * 8);
#pragma unroll
            for (int e = 0; e < 8; e++) q8[e] = (bf16)((float)q8[e] * scale);
            Qf[qt][ks] = q8;
        }
    }

    f32x4 Oacc[2][8] = {};
    float l_i[2] = {0.0f, 0.0f};

    const int krow = tid >> 4;
    const int kblk = tid & 15;
    const int vrow = tid >> 3;   // d row in 32-row slab (USE_VT)
    const int vblk = tid & 7;    // 16B block along s (USE_VT)
    const int vd   = tid & 127;  // legacy
    const int vh   = tid >> 7;   // legacy
    const bf16* Kg  = QKV + 2048 + h * 128;
    const bf16* Vg  = QKV + 4096 + h * 128;
    const bf16* Vtb = QKV + 4096;   // VT layout base

    bf16x8 Kpre[4], Vpre[4];
#pragma unroll
    for (int rr = 0; rr < 4; rr++)
        Kpre[rr] = *(const bf16x8*)(Kg + (size_t)(rr * 16 + krow) * QKV_LD + kblk * 8);
    if (USE_VT) {
#pragma unroll
        for (int u = 0; u < 4; u++) {
            int dh = h * 128 + u * 32 + vrow;
            Vpre[u] = *(const bf16x8*)(Vtb + (size_t)(2 * dh) * QKV_LD + vblk * 8);
        }
    } else {
#pragma unroll
        for (int u = 0; u < 4; u++)
#pragma unroll
            for (int j = 0; j < 8; j++)
                Vpre[u][j] = Vg[(size_t)(vh * 32 + u * 8 + j) * QKV_LD + vd];
    }

    for (int kt = 0; kt < nkv; kt++) {
        const int kbase = kt * 64;
#pragma unroll
        for (int rr = 0; rr < 4; rr++) {
            int kv = rr * 16 + krow;
            *(bf16x8*)&sK[kv * 128 + ((kblk ^ (kv & 7)) * 8)] = Kpre[rr];
        }
        if (USE_VT) {
#pragma unroll
            for (int u = 0; u < 4; u++) {
                int d = u * 32 + vrow;
                *(bf16x8*)&sV[d * 64 + ((vblk ^ (d & 7)) * 8)] = Vpre[u];
            }
        } else {
#pragma unroll
            for (int u = 0; u < 4; u++)
                *(bf16x8*)&sV[vd * 64 + (((vh * 4 + u) ^ (vd & 7)) * 8)] = Vpre[u];
        }
        __syncthreads();
        if (kt + 1 < nkv) {
            const int nb = kbase + 64;
#pragma unroll
            for (int rr = 0; rr < 4; rr++)
                Kpre[rr] = *(const bf16x8*)(Kg + (size_t)(nb + rr * 16 + krow) * QKV_LD + kblk * 8);
            if (USE_VT) {
#pragma unroll
                for (int u = 0; u < 4; u++) {
                    int dh = h * 128 + u * 32 + vrow;
                    Vpre[u] = *(const bf16x8*)(Vtb + (size_t)(2 * dh + (nb >> 11)) * QKV_LD +
                                               (nb & 2047) + vblk * 8);
                }
            } else {
#pragma unroll
                for (int u = 0; u < 4; u++)
#pragma unroll
                    for (int j = 0; j < 8; j++)
                        Vpre[u][j] = Vg[(size_t)(nb + vh * 32 + u * 8 + j) * QKV_LD + vd];
            }
        }
        if (kbase <= qw0 + 31) {
            f32x4 Sacc[2][4] = {};
            __builtin_amdgcn_s_setprio(1);
#pragma unroll
            for (int ks = 0; ks < 4; ks++)
#pragma unroll
                for (int j = 0; j < 4; j++) {
                    bf16x8 af = *(const bf16x8*)&sK[(j * 16 + ln) * 128 + (((ks * 4 + qd) ^ (ln & 7)) * 8)];
                    Sacc[0][j] = __builtin_amdgcn_mfma_f32_16x16x32_bf16(af, Qf[0][ks], Sacc[0][j], 0, 0, 0);
                    Sacc[1][j] = __builtin_amdgcn_mfma_f32_16x16x32_bf16(af, Qf[1][ks], Sacc[1][j], 0, 0, 0);
                }
            __builtin_amdgcn_s_setprio(0);
#pragma unroll
            for (int qt = 0; qt < 2; qt++) {
                const int qs = qw0 + qt * 16;
                if (kbase + 63 > qs) {
#pragma unroll
                    for (int j = 0; j < 4; j++)
#pragma unroll
                        for (int r = 0; r < 4; r++)
                            if (kbase + j * 16 + qd * 4 + r > qs + ln) Sacc[qt][j][r] = -1e30f;
                }
                float psum = 0.0f;
#pragma unroll
                for (int j = 0; j < 4; j++) {
                    bf16x4 p4;
#pragma unroll
                    for (int r = 0; r < 4; r++) {
                        float p = __expf(Sacc[qt][j][r]);
                        psum += p;
                        p4[r] = (bf16)p;
                    }
                    int blk = (j * 2 + (qd >> 1)) ^ (ln & 7);
                    *(bf16x4*)&sP[wave][(qt * 16 + ln) * 64 + blk * 8 + (qd & 1) * 4] = p4;
                }
                psum += __shfl_xor(psum, 16);
                psum += __shfl_xor(psum, 32);
                l_i[qt] += psum;
            }
            __builtin_amdgcn_s_setprio(1);
#pragma unroll
            for (int ks = 0; ks < 2; ks++) {
                bf16x8 pf0 = *(const bf16x8*)&sP[wave][(0 * 16 + ln) * 64 + (((ks * 4 + qd) ^ (ln & 7)) * 8)];
                bf16x8 pf1 = *(const bf16x8*)&sP[wave][(1 * 16 + ln) * 64 + (((ks * 4 + qd) ^ (ln & 7)) * 8)];
#pragma unroll
                for (int dt = 0; dt < 8; dt++) {
                    bf16x8 vf = *(const bf16x8*)&sV[(dt * 16 + ln) * 64 + (((ks * 4 + qd) ^ (ln & 7)) * 8)];
                    Oacc[0][dt] = __builtin_amdgcn_mfma_f32_16x16x32_bf16(pf0, vf, Oacc[0][dt], 0, 0, 0);
                    Oacc[1][dt] = __builtin_amdgcn_mfma_f32_16x16x32_bf16(pf1, vf, Oacc[1][dt], 0, 0, 0);
                }
            }
            __builtin_amdgcn_s_setprio(0);
        }
        __syncthreads();
    }
#pragma unroll
    for (int qt = 0; qt < 2; qt++) {
        float linv[4];
#pragma unroll
        for (int r = 0; r < 4; r++)
            linv[r] = 1.0f / __shfl(l_i[qt], (lane & 48) | (qd * 4 + r));
        bf16* Ob = O + (size_t)(qw0 + qt * 16 + qd * 4) * 2048 + h * 128 + ln;
#pragma unroll
        for (int dt = 0; dt < 8; dt++)
#pragma unroll
            for (int r = 0; r < 4; r++)
                Ob[(size_t)r * 2048 + dt * 16] = (bf16)(Oacc[qt][dt][r] * linv[r]);
    }
}

extern "C" void kernel_launch(void* const* d_in, const int* in_sizes, int n_in,
                              void* d_out, int out_size, void* d_ws, size_t ws_size,
                              hipStream_t stream) {
    const float* X    = (const float*)d_in[0];  // [4096][2048] f32
    const float* Wqkv = (const float*)d_in[1];  // [6144][2048] f32
    const float* Wo   = (const float*)d_in[2];  // [2048][2048] f32
    float* out = (float*)d_out;                 // [4096][2048] f32
    bf16* QKV = (bf16*)d_ws;                    // [4096][6144] bf16
    bf16* ATT = QKV + (size_t)4096 * 6144;      // [4096][2048] bf16

    const size_t nX = (size_t)4096 * 2048, nWq = (size_t)6144 * 2048, nWo = (size_t)2048 * 2048;
    const size_t need = (nX * 3 + nWq * 2 + nWo) * 2 + nX * 2;

    if (ws_size >= need) {
        bf16* Xb  = ATT + nX;
        bf16* Wqb = Xb + nX;
        bf16* Wob = Wqb + nWq;
        float* Tab = (float*)ATT;   // ATT dead until flash -> RoPE table (2 MB)
        prep<<<13312, 256, 0, stream>>>(X, Xb, Wqkv, Wqb, Wo, Wob, Tab);
        gemm256_nt<1><<<dim3(16, 24), 512, 0, stream>>>(Xb, Wqb, QKV, 4096, 6144, 2048, Tab);
        flash_attn<1><<<dim3(HNUM, 32), 256, 0, stream>>>(QKV, ATT);
        gemm128x256<1><<<dim3(32, 8), 512, 0, stream>>>(ATT, Wob, out, 4096, 2048, 2048);
    } else {
        gemm_nt<1, 1, 0><<<dim3(32, 48), 256, 0, stream>>>(X, Wqkv, QKV, 4096, 6144, 2048);
        rope_k_inline<<<dim3(4096, 8), 256, 0, stream>>>(QKV);
        flash_attn<0><<<dim3(HNUM, 32), 256, 0, stream>>>(QKV, ATT);
        gemm_nt<0, 1, 1><<<dim3(32, 16), 256, 0, stream>>>(ATT, Wo, out, 4096, 2048, 2048);
    }
}